// Round 6
// baseline (172.185 us; speedup 1.0000x reference)
//
#include <hip/hip_runtime.h>
#include <math.h>

#define NC 6
#define RM 16
#define TOPK 10
#define BSZ 32
#define G 20
#define A_TOT 8400
#define NBA (BSZ * A_TOT)
#define NBLK_PREP (NBA / 256)          /* 1050: one thread per (quad, side) */
#define APT 8                          /* anchors per thread in k_loss */
#define NBLK_LOSS ((NBA + 256 * APT - 1) / (256 * APT))   /* 132 */
#define MAXCAND 1024

__device__ __forceinline__ void anchor_decode(int a, int& lvl, int& ai, int& w, int& hw, float& s) {
    if (a < 6400)      { lvl = 0; ai = a;        w = 80; hw = 6400; s = 8.f; }
    else if (a < 8000) { lvl = 1; ai = a - 6400; w = 40; hw = 1600; s = 16.f; }
    else               { lvl = 2; ai = a - 8000; w = 20; hw = 400;  s = 32.f; }
}

// task-aligned metric for one (gt, anchor) pair; returns 0 if anchor center not in gt
__device__ __forceinline__ float align_from(const float* __restrict__ trow, float logit,
                                            float4 box, float ax, float ay) {
    float cx = trow[2] * 640.f, cy = trow[3] * 640.f;
    float hwd = trow[4] * 320.f, hh = trow[5] * 320.f;
    float gx1 = cx - hwd, gy1 = cy - hh, gx2 = cx + hwd, gy2 = cy + hh;
    float mn = fminf(fminf(ax - gx1, ay - gy1), fminf(gx2 - ax, gy2 - ay));
    if (mn <= 1e-9f) return 0.f;
    const float eps = 1e-7f;
    float x1 = fmaxf(gx1, box.x), y1 = fmaxf(gy1, box.y);
    float x2 = fminf(gx2, box.z), y2 = fminf(gy2, box.w);
    float inter = fmaxf(x2 - x1, 0.f) * fmaxf(y2 - y1, 0.f);
    float gw = fmaxf(gx2 - gx1, eps), gh = fmaxf(gy2 - gy1, eps);
    float w2 = fmaxf(box.z - box.x, eps), h2 = fmaxf(box.w - box.y, eps);
    float uni = gw * gh + w2 * h2 - inter + eps;
    float iou = inter / uni;
    float sc = 1.f / (1.f + __expf(-logit));
    float i2 = iou * iou;
    return sqrtf(sc) * (i2 * i2 * i2);
}

// ------- Kernel 1: decode boxes, logZ, base BCE, zero mask + done counter -------
// Quad-split: 4 threads per quad of consecutive anchors; thread sd does side sd's
// 16-channel single-pass softmax (no max subtraction: inputs are O(5), no overflow).
__global__ __launch_bounds__(256) void k_prep(
        const float* __restrict__ p0, const float* __restrict__ p1, const float* __restrict__ p2,
        float* __restrict__ pd_boxes, float* __restrict__ logZ,
        unsigned int* __restrict__ mask, float* __restrict__ partial_prep,
        unsigned int* __restrict__ done) {
    __shared__ float sdist[256 * 4];
    __shared__ float slz[256 * 4];
    int tid = blockIdx.x * 256 + threadIdx.x;
    int q = tid >> 2;           // quad index
    int sd = tid & 3;           // side handled by this thread
    int idx4 = q * 4;
    int b = idx4 / A_TOT, a4 = idx4 % A_TOT;
    int lvl, ai, w, hw; float s;
    anchor_decode(a4, lvl, ai, w, hw, s);
    const float* p = (lvl == 0) ? p0 : ((lvl == 1) ? p1 : p2);
    const float* base = p + (size_t)b * 70 * hw + ai;

    float4 se = make_float4(0, 0, 0, 0), sk = make_float4(0, 0, 0, 0);
    #pragma unroll
    for (int k = 0; k < RM; ++k) {
        float4 v = *(const float4*)(base + (size_t)(sd * RM + k) * hw);
        float fk = (float)k;
        float ex = __expf(v.x); se.x += ex; sk.x += ex * fk;
        float ey = __expf(v.y); se.y += ey; sk.y += ey * fk;
        float ez = __expf(v.z); se.z += ez; sk.z += ez * fk;
        float ew = __expf(v.w); se.w += ew; sk.w += ew * fk;
    }
    ((float4*)sdist)[threadIdx.x] =
        make_float4(sk.x / se.x, sk.y / se.y, sk.z / se.z, sk.w / se.w);
    ((float4*)slz)[threadIdx.x] =
        make_float4(__logf(se.x), __logf(se.y), __logf(se.z), __logf(se.w));

    // base BCE (target=0 term) for class channels 64+sd (+68+sd for sd<2)
    float bce = 0.f;
    {
        float4 x = *(const float4*)(base + (size_t)(64 + sd) * hw);
        bce += fmaxf(x.x, 0.f) + __logf(1.f + __expf(-fabsf(x.x)));
        bce += fmaxf(x.y, 0.f) + __logf(1.f + __expf(-fabsf(x.y)));
        bce += fmaxf(x.z, 0.f) + __logf(1.f + __expf(-fabsf(x.z)));
        bce += fmaxf(x.w, 0.f) + __logf(1.f + __expf(-fabsf(x.w)));
        if (sd < 2) {
            float4 y = *(const float4*)(base + (size_t)(68 + sd) * hw);
            bce += fmaxf(y.x, 0.f) + __logf(1.f + __expf(-fabsf(y.x)));
            bce += fmaxf(y.y, 0.f) + __logf(1.f + __expf(-fabsf(y.y)));
            bce += fmaxf(y.z, 0.f) + __logf(1.f + __expf(-fabsf(y.z)));
            bce += fmaxf(y.w, 0.f) + __logf(1.f + __expf(-fabsf(y.w)));
        }
    }
    mask[tid] = 0u;
    if (tid == 0) *done = 0u;
    __syncthreads();

    // thread sd writes anchor (quad, j=sd): gather its 4 sides from LDS
    int gb = (threadIdx.x & ~3) * 4;
    float d0 = sdist[gb + sd], d1 = sdist[gb + 4 + sd];
    float d2 = sdist[gb + 8 + sd], d3 = sdist[gb + 12 + sd];
    float z0 = slz[gb + sd], z1 = slz[gb + 4 + sd];
    float z2 = slz[gb + 8 + sd], z3 = slz[gb + 12 + sd];
    float ax = ((float)(ai % w + sd) + 0.5f) * s;
    float ay = ((float)(ai / w) + 0.5f) * s;
    ((float4*)pd_boxes)[tid] = make_float4(ax - d0 * s, ay - d1 * s, ax + d2 * s, ay + d3 * s);
    ((float4*)logZ)[tid] = make_float4(z0, z1, z2, z3);

    // block reduce bce
    __shared__ float part[4];
    int lane = threadIdx.x & 63, wv = threadIdx.x >> 6;
    #pragma unroll
    for (int off = 32; off > 0; off >>= 1) bce += __shfl_down(bce, off);
    if (lane == 0) part[wv] = bce;
    __syncthreads();
    if (threadIdx.x == 0)
        partial_prep[blockIdx.x] = part[0] + part[1] + part[2] + part[3];
}

// prefer higher value; on tie prefer LOWER index (matches jax.lax.top_k)
__device__ __forceinline__ bool cand_better(float av, int ai_, float bv, int bi_) {
    if (av > bv) return true;
    if (av < bv) return false;
    if (ai_ < 0) return false;
    if (bi_ < 0) return true;
    return ai_ < bi_;
}

// ------- Kernel 2: per-(b,g) bounded cell scan + top-10 -> mask bits, row max -------
__global__ __launch_bounds__(256) void k_align(
        const float* __restrict__ targets,
        const float* __restrict__ pd_boxes,
        const float* __restrict__ p0, const float* __restrict__ p1, const float* __restrict__ p2,
        float* __restrict__ amax, unsigned int* __restrict__ mask) {
    __shared__ float cval[MAXCAND];
    __shared__ int   cidx[MAXCAND];
    __shared__ int   cnt_s;
    __shared__ float rv[4];
    __shared__ int   ri[4];
    __shared__ int   win_i_s;

    int bg = blockIdx.x;
    int b = bg / G;
    int g = bg % G;
    const float* t = targets + (size_t)bg * 6;
    int lab = (int)t[1];
    const float* cb[3];
    cb[0] = p0 + (size_t)b * 70 * 6400 + (size_t)(64 + lab) * 6400;
    cb[1] = p1 + (size_t)b * 70 * 1600 + (size_t)(64 + lab) * 1600;
    cb[2] = p2 + (size_t)b * 70 * 400  + (size_t)(64 + lab) * 400;
    const float4* pb = (const float4*)pd_boxes + (size_t)b * A_TOT;

    float cx = t[2] * 640.f, cy = t[3] * 640.f;
    float hwd = t[4] * 320.f, hh = t[5] * 320.f;
    float gx1 = cx - hwd, gy1 = cy - hh, gx2 = cx + hwd, gy2 = cy + hh;

    // conservative per-level cell rectangles containing all in-box anchor centers
    const float sv3[3] = {8.f, 16.f, 32.f};
    const int   wv3[3] = {80, 40, 20};
    const int   ov3[3] = {0, 6400, 8000};
    int x0[3], y0[3], nx[3], ncell[3];
    int ntot = 0;
    #pragma unroll
    for (int l = 0; l < 3; ++l) {
        float s = sv3[l]; int w = wv3[l];
        int xa = max(0, (int)floorf(gx1 / s - 0.5f));
        int xb = min(w - 1, (int)ceilf(gx2 / s - 0.5f));
        int ya = max(0, (int)floorf(gy1 / s - 0.5f));
        int yb = min(w - 1, (int)ceilf(gy2 / s - 0.5f));
        x0[l] = xa; y0[l] = ya;
        nx[l] = max(0, xb - xa + 1);
        int nyl = max(0, yb - ya + 1);
        ncell[l] = nx[l] * nyl;
        ntot += ncell[l];
    }

    if (threadIdx.x == 0) cnt_s = 0;
    __syncthreads();

    for (int i = threadIdx.x; i < ntot; i += 256) {
        int l = 0, loc = i;
        if (loc >= ncell[0]) { loc -= ncell[0]; l = 1; }
        if (l == 1 && loc >= ncell[1]) { loc -= ncell[1]; l = 2; }
        int iy = loc / nx[l], ix = loc % nx[l];
        ix += x0[l]; iy += y0[l];
        float s = sv3[l]; int w = wv3[l];
        float ax = ((float)ix + 0.5f) * s, ay = ((float)iy + 0.5f) * s;
        int a = ov3[l] + iy * w + ix;
        float logit = cb[l][iy * w + ix];
        float al = align_from(t, logit, pb[a], ax, ay);
        if (al > 0.f) {
            int p = atomicAdd(&cnt_s, 1);
            if (p < MAXCAND) { cval[p] = al; cidx[p] = a; }
        }
    }
    __syncthreads();
    int cnt = min(cnt_s, MAXCAND);

    float mv[MAXCAND / 256];
    int   mi[MAXCAND / 256];
    #pragma unroll
    for (int r = 0; r < MAXCAND / 256; ++r) {
        int p = threadIdx.x + r * 256;
        mv[r] = (p < cnt) ? cval[p] : -1.f;
        mi[r] = (p < cnt) ? cidx[p] : -1;
    }

    int lane = threadIdx.x & 63, wv = threadIdx.x >> 6;
    for (int it = 0; it < TOPK; ++it) {
        float v = -1.f; int vi = -1;
        #pragma unroll
        for (int r = 0; r < MAXCAND / 256; ++r)
            if (cand_better(mv[r], mi[r], v, vi)) { v = mv[r]; vi = mi[r]; }
        #pragma unroll
        for (int off = 32; off > 0; off >>= 1) {
            float ov = __shfl_down(v, off);
            int   oi = __shfl_down(vi, off);
            if (cand_better(ov, oi, v, vi)) { v = ov; vi = oi; }
        }
        if (lane == 0) { rv[wv] = v; ri[wv] = vi; }
        __syncthreads();
        if (threadIdx.x == 0) {
            float v0 = rv[0]; int i0 = ri[0];
            for (int i = 1; i < 4; ++i)
                if (cand_better(rv[i], ri[i], v0, i0)) { v0 = rv[i]; i0 = ri[i]; }
            if (it == 0) amax[bg] = fmaxf(v0, 0.f);
            if (i0 >= 0 && v0 > 0.f) atomicOr(&mask[(size_t)b * A_TOT + i0], 1u << g);
            win_i_s = i0;
        }
        __syncthreads();
        int wi = win_i_s;
        if (wi < 0) break;
        #pragma unroll
        for (int r = 0; r < MAXCAND / 256; ++r)
            if (mi[r] == wi) { mv[r] = -1.f; mi[r] = -1; }
    }
}

// per-anchor loss body; accumulates into the 4 sums
__device__ __forceinline__ void loss_anchor(
        int idx, const float* __restrict__ targets,
        const float* __restrict__ pd_boxes, const float* __restrict__ logZ,
        const float* __restrict__ amax, const unsigned int* __restrict__ mask,
        const float* __restrict__ p0, const float* __restrict__ p1, const float* __restrict__ p2,
        float& bce_s, float& bbox_s, float& dfl_s, float& fg_s) {
    unsigned int m = mask[idx];
    if (m == 0u) return;
    int b = idx / A_TOT, a = idx % A_TOT;
    int lvl, ai, w_, hw; float s;
    anchor_decode(a, lvl, ai, w_, hw, s);
    const float* p = (lvl == 0) ? p0 : ((lvl == 1) ? p1 : p2);
    const float* base = p + (size_t)b * 70 * hw + ai;
    float ax = ((ai % w_) + 0.5f) * s, ay = ((ai / w_) + 0.5f) * s;
    float4 box = ((const float4*)pd_boxes)[idx];
    int gidx;
    if (__popc(m) > 1) {
        float best = -1.f; gidx = 0;
        for (int g = 0; g < G; ++g) {
            const float* tg = targets + ((size_t)b * G + g) * 6;
            int labg = (int)tg[1];
            float al = align_from(tg, base[(size_t)(64 + labg) * hw], box, ax, ay);
            if (al > best) { best = al; gidx = g; }
        }
    } else {
        gidx = __ffs(m) - 1;
    }
    const float* t = targets + ((size_t)b * G + gidx) * 6;
    int lab = (int)t[1];
    float logit = base[(size_t)(64 + lab) * hw];
    float al = align_from(t, logit, box, ax, ay);
    float cx = t[2] * 640.f, cy = t[3] * 640.f;
    float hwd = t[4] * 320.f, hh = t[5] * 320.f;
    float tbx1 = cx - hwd, tby1 = cy - hh, tbx2 = cx + hwd, tby2 = cy + hh;
    const float eps = 1e-7f;
    float x1 = fmaxf(box.x, tbx1), y1 = fmaxf(box.y, tby1);
    float x2 = fminf(box.z, tbx2), y2 = fminf(box.w, tby2);
    float inter = fmaxf(x2 - x1, 0.f) * fmaxf(y2 - y1, 0.f);
    float w1 = fmaxf(box.z - box.x, eps), h1 = fmaxf(box.w - box.y, eps);
    float w2 = fmaxf(tbx2 - tbx1, eps), h2 = fmaxf(tby2 - tby1, eps);
    float uni = w1 * h1 + w2 * h2 - inter + eps;
    float iou = inter / uni;
    float iou_fg = fmaxf(iou, 0.f);
    float sval = (al / (amax[b * G + gidx] + 1e-9f)) * iou_fg;
    bce_s += -logit * sval;          // BCE correction for target!=0
    fg_s += 1.f;
    // CIoU
    float cw = fmaxf(box.z, tbx2) - fminf(box.x, tbx1);
    float ch = fmaxf(box.w, tby2) - fminf(box.y, tby1);
    float c2 = cw * cw + ch * ch + eps;
    float dx = box.x + box.z - tbx1 - tbx2;
    float dy = box.y + box.w - tby1 - tby2;
    float rho2 = (dx * dx + dy * dy) * 0.25f;
    float dv = atanf(w2 / h2) - atanf(w1 / h1);
    float v = 0.40528473f * dv * dv;            // 4/pi^2
    float alpha = v / (v - iou + (1.f + eps));
    float ciou = iou - (rho2 / c2 + v * alpha);
    bbox_s += 1.f - ciou;
    // DFL
    float4 lzv = ((const float4*)logZ)[idx];
    float lz[4] = {lzv.x, lzv.y, lzv.z, lzv.w};
    float lt[4] = {(ax - tbx1) / s, (ay - tby1) / s, (tbx2 - ax) / s, (tby2 - ay) / s};
    #pragma unroll
    for (int sd = 0; sd < 4; ++sd) {
        float d = fminf(fmaxf(lt[sd], 0.f), (float)RM - 1.01f);
        int tl = (int)d;
        float wl = (float)(tl + 1) - d;
        float wr = d - (float)tl;
        float xl = base[(size_t)(sd * RM + tl) * hw];
        float xr = base[(size_t)(sd * RM + tl + 1) * hw];
        dfl_s += (lz[sd] - xl) * wl + (lz[sd] - xr) * wr;
    }
}

// ------- Kernel 3: fg-only losses (8 anchors/thread) + fused last-block final -------
__global__ __launch_bounds__(256) void k_loss(
        const float* __restrict__ targets,
        const float* __restrict__ pd_boxes, const float* __restrict__ logZ,
        const float* __restrict__ amax, const unsigned int* __restrict__ mask,
        const float* __restrict__ p0, const float* __restrict__ p1, const float* __restrict__ p2,
        float* __restrict__ partial, const float* __restrict__ partial_prep,
        unsigned int* __restrict__ done, float* __restrict__ out) {
    float bce_s = 0.f, bbox_s = 0.f, dfl_s = 0.f, fg_s = 0.f;
    int base_idx = blockIdx.x * 256 * APT + threadIdx.x;
    #pragma unroll
    for (int r = 0; r < APT; ++r) {
        int idx = base_idx + r * 256;
        if (idx < NBA)
            loss_anchor(idx, targets, pd_boxes, logZ, amax, mask, p0, p1, p2,
                        bce_s, bbox_s, dfl_s, fg_s);
    }
    __shared__ float part[4][4];
    int lane = threadIdx.x & 63, wv = threadIdx.x >> 6;
    #pragma unroll
    for (int off = 32; off > 0; off >>= 1) {
        bce_s  += __shfl_down(bce_s,  off);
        bbox_s += __shfl_down(bbox_s, off);
        dfl_s  += __shfl_down(dfl_s,  off);
        fg_s   += __shfl_down(fg_s,   off);
    }
    if (lane == 0) {
        part[wv][0] = bce_s; part[wv][1] = bbox_s;
        part[wv][2] = dfl_s; part[wv][3] = fg_s;
    }
    __syncthreads();
    __shared__ int is_last;
    if (threadIdx.x == 0) {
        float s0 = 0.f, s1 = 0.f, s2 = 0.f, s3 = 0.f;
        for (int i = 0; i < 4; ++i) {
            s0 += part[i][0]; s1 += part[i][1]; s2 += part[i][2]; s3 += part[i][3];
        }
        ((float4*)partial)[blockIdx.x] = make_float4(s0, s1, s2, s3);
        __threadfence();                                  // publish partial
        unsigned int old = atomicAdd(done, 1u);
        is_last = (old == (unsigned int)(NBLK_LOSS - 1));
    }
    __syncthreads();
    if (!is_last) return;
    __threadfence();                                      // acquire all partials

    double s0 = 0., s1 = 0., s2 = 0., s3 = 0.;
    for (int i = threadIdx.x; i < NBLK_LOSS; i += 256) {
        float4 p = ((const float4*)partial)[i];
        s0 += p.x; s1 += p.y; s2 += p.z; s3 += p.w;
    }
    for (int i = threadIdx.x; i < NBLK_PREP; i += 256)
        s0 += partial_prep[i];
    #pragma unroll
    for (int off = 32; off > 0; off >>= 1) {
        s0 += __shfl_down(s0, off);
        s1 += __shfl_down(s1, off);
        s2 += __shfl_down(s2, off);
        s3 += __shfl_down(s3, off);
    }
    __shared__ double dpart[4][4];
    if (lane == 0) { dpart[wv][0] = s0; dpart[wv][1] = s1; dpart[wv][2] = s2; dpart[wv][3] = s3; }
    __syncthreads();
    if (threadIdx.x == 0) {
        double bce = 0., bbox = 0., dfl = 0., fgc = 0.;
        for (int i = 0; i < 4; ++i) {
            bce += dpart[i][0]; bbox += dpart[i][1]; dfl += dpart[i][2]; fgc += dpart[i][3];
        }
        double l_cls = bce / (double)A_TOT;
        double np_ = fmax(fgc, 1.0);
        double l_bbox = 7.5 * bbox / np_;
        double l_dfl = 1.5 * dfl / np_;
        out[0] = (float)(l_cls + l_bbox + l_dfl);
        out[1] = (float)l_cls;
        out[2] = (float)l_bbox;
        out[3] = 0.f;
        out[4] = (float)l_dfl;
    }
}

extern "C" void kernel_launch(void* const* d_in, const int* in_sizes, int n_in,
                              void* d_out, int out_size, void* d_ws, size_t ws_size,
                              hipStream_t stream) {
    const float* p0 = (const float*)d_in[0];
    const float* p1 = (const float*)d_in[1];
    const float* p2 = (const float*)d_in[2];
    const float* targets = (const float*)d_in[3];
    float* out = (float*)d_out;

    char* ws = (char*)d_ws;
    size_t off = 0;
    float* pd_boxes = (float*)(ws + off); off += (size_t)NBA * 4 * sizeof(float);
    float* logZ     = (float*)(ws + off); off += (size_t)NBA * 4 * sizeof(float);
    float* amax     = (float*)(ws + off); off += (size_t)BSZ * G * sizeof(float);
    unsigned int* mask = (unsigned int*)(ws + off); off += (size_t)NBA * sizeof(unsigned int);
    float* partial  = (float*)(ws + off); off += (size_t)NBLK_LOSS * 4 * sizeof(float);
    float* partial_prep = (float*)(ws + off); off += (size_t)NBLK_PREP * sizeof(float);
    unsigned int* done = (unsigned int*)(ws + off); off += sizeof(unsigned int);

    k_prep<<<NBLK_PREP, 256, 0, stream>>>(p0, p1, p2, pd_boxes, logZ, mask,
                                          partial_prep, done);
    k_align<<<BSZ * G, 256, 0, stream>>>(targets, pd_boxes, p0, p1, p2, amax, mask);
    k_loss<<<NBLK_LOSS, 256, 0, stream>>>(targets, pd_boxes, logZ, amax, mask,
                                          p0, p1, p2, partial, partial_prep, done, out);
}

// Round 7
// 143.897 us; speedup vs baseline: 1.1966x; 1.1966x over previous
//
#include <hip/hip_runtime.h>
#include <math.h>

#define NC 6
#define RM 16
#define TOPK 10
#define BSZ 32
#define G 20
#define A_TOT 8400
#define NBA (BSZ * A_TOT)
#define NBLK_PREP (NBA / 256)          /* 1050: one thread per (quad, side) */
#define NBLK_LOSS ((NBA + 255) / 256)  /* 1050: one anchor per thread */
#define MAXCAND 1024

__device__ __forceinline__ void anchor_decode(int a, int& lvl, int& ai, int& w, int& hw, float& s) {
    if (a < 6400)      { lvl = 0; ai = a;        w = 80; hw = 6400; s = 8.f; }
    else if (a < 8000) { lvl = 1; ai = a - 6400; w = 40; hw = 1600; s = 16.f; }
    else               { lvl = 2; ai = a - 8000; w = 20; hw = 400;  s = 32.f; }
}

// task-aligned metric for one (gt, anchor) pair; returns 0 if anchor center not in gt
__device__ __forceinline__ float align_from(const float* __restrict__ trow, float logit,
                                            float4 box, float ax, float ay) {
    float cx = trow[2] * 640.f, cy = trow[3] * 640.f;
    float hwd = trow[4] * 320.f, hh = trow[5] * 320.f;
    float gx1 = cx - hwd, gy1 = cy - hh, gx2 = cx + hwd, gy2 = cy + hh;
    float mn = fminf(fminf(ax - gx1, ay - gy1), fminf(gx2 - ax, gy2 - ay));
    if (mn <= 1e-9f) return 0.f;
    const float eps = 1e-7f;
    float x1 = fmaxf(gx1, box.x), y1 = fmaxf(gy1, box.y);
    float x2 = fminf(gx2, box.z), y2 = fminf(gy2, box.w);
    float inter = fmaxf(x2 - x1, 0.f) * fmaxf(y2 - y1, 0.f);
    float gw = fmaxf(gx2 - gx1, eps), gh = fmaxf(gy2 - gy1, eps);
    float w2 = fmaxf(box.z - box.x, eps), h2 = fmaxf(box.w - box.y, eps);
    float uni = gw * gh + w2 * h2 - inter + eps;
    float iou = inter / uni;
    float sc = 1.f / (1.f + __expf(-logit));
    float i2 = iou * iou;
    return sqrtf(sc) * (i2 * i2 * i2);
}

// ------- Kernel 1: decode boxes, logZ, base BCE, zero mask -------
// Quad-split: 4 threads per quad of consecutive anchors; thread sd does side sd's
// 16-channel single-pass softmax (no max subtraction: inputs are O(5), no overflow).
__global__ __launch_bounds__(256) void k_prep(
        const float* __restrict__ p0, const float* __restrict__ p1, const float* __restrict__ p2,
        float* __restrict__ pd_boxes, float* __restrict__ logZ,
        unsigned int* __restrict__ mask, float* __restrict__ partial_prep) {
    __shared__ float sdist[256 * 4];
    __shared__ float slz[256 * 4];
    int tid = blockIdx.x * 256 + threadIdx.x;
    int q = tid >> 2;           // quad index
    int sd = tid & 3;           // side handled by this thread
    int idx4 = q * 4;
    int b = idx4 / A_TOT, a4 = idx4 % A_TOT;
    int lvl, ai, w, hw; float s;
    anchor_decode(a4, lvl, ai, w, hw, s);
    const float* p = (lvl == 0) ? p0 : ((lvl == 1) ? p1 : p2);
    const float* base = p + (size_t)b * 70 * hw + ai;

    float4 se = make_float4(0, 0, 0, 0), sk = make_float4(0, 0, 0, 0);
    #pragma unroll
    for (int k = 0; k < RM; ++k) {
        float4 v = *(const float4*)(base + (size_t)(sd * RM + k) * hw);
        float fk = (float)k;
        float ex = __expf(v.x); se.x += ex; sk.x += ex * fk;
        float ey = __expf(v.y); se.y += ey; sk.y += ey * fk;
        float ez = __expf(v.z); se.z += ez; sk.z += ez * fk;
        float ew = __expf(v.w); se.w += ew; sk.w += ew * fk;
    }
    ((float4*)sdist)[threadIdx.x] =
        make_float4(sk.x / se.x, sk.y / se.y, sk.z / se.z, sk.w / se.w);
    ((float4*)slz)[threadIdx.x] =
        make_float4(__logf(se.x), __logf(se.y), __logf(se.z), __logf(se.w));

    // base BCE (target=0 term) for class channels 64+sd (+68+sd for sd<2)
    float bce = 0.f;
    {
        float4 x = *(const float4*)(base + (size_t)(64 + sd) * hw);
        bce += fmaxf(x.x, 0.f) + __logf(1.f + __expf(-fabsf(x.x)));
        bce += fmaxf(x.y, 0.f) + __logf(1.f + __expf(-fabsf(x.y)));
        bce += fmaxf(x.z, 0.f) + __logf(1.f + __expf(-fabsf(x.z)));
        bce += fmaxf(x.w, 0.f) + __logf(1.f + __expf(-fabsf(x.w)));
        if (sd < 2) {
            float4 y = *(const float4*)(base + (size_t)(68 + sd) * hw);
            bce += fmaxf(y.x, 0.f) + __logf(1.f + __expf(-fabsf(y.x)));
            bce += fmaxf(y.y, 0.f) + __logf(1.f + __expf(-fabsf(y.y)));
            bce += fmaxf(y.z, 0.f) + __logf(1.f + __expf(-fabsf(y.z)));
            bce += fmaxf(y.w, 0.f) + __logf(1.f + __expf(-fabsf(y.w)));
        }
    }
    mask[tid] = 0u;
    __syncthreads();

    // thread sd writes anchor (quad, j=sd): gather its 4 sides from LDS
    int gb = (threadIdx.x & ~3) * 4;
    float d0 = sdist[gb + sd], d1 = sdist[gb + 4 + sd];
    float d2 = sdist[gb + 8 + sd], d3 = sdist[gb + 12 + sd];
    float z0 = slz[gb + sd], z1 = slz[gb + 4 + sd];
    float z2 = slz[gb + 8 + sd], z3 = slz[gb + 12 + sd];
    float ax = ((float)(ai % w + sd) + 0.5f) * s;
    float ay = ((float)(ai / w) + 0.5f) * s;
    ((float4*)pd_boxes)[tid] = make_float4(ax - d0 * s, ay - d1 * s, ax + d2 * s, ay + d3 * s);
    ((float4*)logZ)[tid] = make_float4(z0, z1, z2, z3);

    // block reduce bce
    __shared__ float part[4];
    int lane = threadIdx.x & 63, wv = threadIdx.x >> 6;
    #pragma unroll
    for (int off = 32; off > 0; off >>= 1) bce += __shfl_down(bce, off);
    if (lane == 0) part[wv] = bce;
    __syncthreads();
    if (threadIdx.x == 0)
        partial_prep[blockIdx.x] = part[0] + part[1] + part[2] + part[3];
}

// prefer higher value; on tie prefer LOWER index (matches jax.lax.top_k)
__device__ __forceinline__ bool cand_better(float av, int ai_, float bv, int bi_) {
    if (av > bv) return true;
    if (av < bv) return false;
    if (ai_ < 0) return false;
    if (bi_ < 0) return true;
    return ai_ < bi_;
}

// ------- Kernel 2: per-(b,g) bounded cell scan + top-10 -> mask bits, row max -------
__global__ __launch_bounds__(256) void k_align(
        const float* __restrict__ targets,
        const float* __restrict__ pd_boxes,
        const float* __restrict__ p0, const float* __restrict__ p1, const float* __restrict__ p2,
        float* __restrict__ amax, unsigned int* __restrict__ mask) {
    __shared__ float cval[MAXCAND];
    __shared__ int   cidx[MAXCAND];
    __shared__ int   cnt_s;
    __shared__ float rv[4];
    __shared__ int   ri[4];
    __shared__ int   win_i_s;

    int bg = blockIdx.x;
    int b = bg / G;
    int g = bg % G;
    const float* t = targets + (size_t)bg * 6;
    int lab = (int)t[1];
    const float* cb[3];
    cb[0] = p0 + (size_t)b * 70 * 6400 + (size_t)(64 + lab) * 6400;
    cb[1] = p1 + (size_t)b * 70 * 1600 + (size_t)(64 + lab) * 1600;
    cb[2] = p2 + (size_t)b * 70 * 400  + (size_t)(64 + lab) * 400;
    const float4* pb = (const float4*)pd_boxes + (size_t)b * A_TOT;

    float cx = t[2] * 640.f, cy = t[3] * 640.f;
    float hwd = t[4] * 320.f, hh = t[5] * 320.f;
    float gx1 = cx - hwd, gy1 = cy - hh, gx2 = cx + hwd, gy2 = cy + hh;

    // conservative per-level cell rectangles containing all in-box anchor centers
    const float sv3[3] = {8.f, 16.f, 32.f};
    const int   wv3[3] = {80, 40, 20};
    const int   ov3[3] = {0, 6400, 8000};
    int x0[3], y0[3], nx[3], ncell[3];
    int ntot = 0;
    #pragma unroll
    for (int l = 0; l < 3; ++l) {
        float s = sv3[l]; int w = wv3[l];
        int xa = max(0, (int)floorf(gx1 / s - 0.5f));
        int xb = min(w - 1, (int)ceilf(gx2 / s - 0.5f));
        int ya = max(0, (int)floorf(gy1 / s - 0.5f));
        int yb = min(w - 1, (int)ceilf(gy2 / s - 0.5f));
        x0[l] = xa; y0[l] = ya;
        nx[l] = max(0, xb - xa + 1);
        int nyl = max(0, yb - ya + 1);
        ncell[l] = nx[l] * nyl;
        ntot += ncell[l];
    }

    if (threadIdx.x == 0) cnt_s = 0;
    __syncthreads();

    for (int i = threadIdx.x; i < ntot; i += 256) {
        int l = 0, loc = i;
        if (loc >= ncell[0]) { loc -= ncell[0]; l = 1; }
        if (l == 1 && loc >= ncell[1]) { loc -= ncell[1]; l = 2; }
        int iy = loc / nx[l], ix = loc % nx[l];
        ix += x0[l]; iy += y0[l];
        float s = sv3[l]; int w = wv3[l];
        float ax = ((float)ix + 0.5f) * s, ay = ((float)iy + 0.5f) * s;
        int a = ov3[l] + iy * w + ix;
        float logit = cb[l][iy * w + ix];
        float al = align_from(t, logit, pb[a], ax, ay);
        if (al > 0.f) {
            int p = atomicAdd(&cnt_s, 1);
            if (p < MAXCAND) { cval[p] = al; cidx[p] = a; }
        }
    }
    __syncthreads();
    int cnt = min(cnt_s, MAXCAND);

    float mv[MAXCAND / 256];
    int   mi[MAXCAND / 256];
    #pragma unroll
    for (int r = 0; r < MAXCAND / 256; ++r) {
        int p = threadIdx.x + r * 256;
        mv[r] = (p < cnt) ? cval[p] : -1.f;
        mi[r] = (p < cnt) ? cidx[p] : -1;
    }

    int lane = threadIdx.x & 63, wv = threadIdx.x >> 6;
    for (int it = 0; it < TOPK; ++it) {
        float v = -1.f; int vi = -1;
        #pragma unroll
        for (int r = 0; r < MAXCAND / 256; ++r)
            if (cand_better(mv[r], mi[r], v, vi)) { v = mv[r]; vi = mi[r]; }
        #pragma unroll
        for (int off = 32; off > 0; off >>= 1) {
            float ov = __shfl_down(v, off);
            int   oi = __shfl_down(vi, off);
            if (cand_better(ov, oi, v, vi)) { v = ov; vi = oi; }
        }
        if (lane == 0) { rv[wv] = v; ri[wv] = vi; }
        __syncthreads();
        if (threadIdx.x == 0) {
            float v0 = rv[0]; int i0 = ri[0];
            for (int i = 1; i < 4; ++i)
                if (cand_better(rv[i], ri[i], v0, i0)) { v0 = rv[i]; i0 = ri[i]; }
            if (it == 0) amax[bg] = fmaxf(v0, 0.f);
            if (i0 >= 0 && v0 > 0.f) atomicOr(&mask[(size_t)b * A_TOT + i0], 1u << g);
            win_i_s = i0;
        }
        __syncthreads();
        int wi = win_i_s;
        if (wi < 0) break;
        #pragma unroll
        for (int r = 0; r < MAXCAND / 256; ++r)
            if (mi[r] == wi) { mv[r] = -1.f; mi[r] = -1; }
    }
}

// ------- Kernel 3: fg-only losses (1 anchor/thread, 1050 blocks), per-block partials -------
__global__ __launch_bounds__(256) void k_loss(
        const float* __restrict__ targets,
        const float* __restrict__ pd_boxes, const float* __restrict__ logZ,
        const float* __restrict__ amax, const unsigned int* __restrict__ mask,
        const float* __restrict__ p0, const float* __restrict__ p1, const float* __restrict__ p2,
        float* __restrict__ partial) {
    int idx = blockIdx.x * 256 + threadIdx.x;
    float bce_s = 0.f, bbox_s = 0.f, dfl_s = 0.f, fg_s = 0.f;
    if (idx < NBA) {
        unsigned int m = mask[idx];
        if (m != 0u) {
            int b = idx / A_TOT, a = idx % A_TOT;
            int lvl, ai, w_, hw; float s;
            anchor_decode(a, lvl, ai, w_, hw, s);
            const float* p = (lvl == 0) ? p0 : ((lvl == 1) ? p1 : p2);
            const float* base = p + (size_t)b * 70 * hw + ai;
            float ax = ((ai % w_) + 0.5f) * s, ay = ((ai / w_) + 0.5f) * s;
            float4 box = ((const float4*)pd_boxes)[idx];
            int gidx;
            if (__popc(m) > 1) {
                float best = -1.f; gidx = 0;
                for (int g = 0; g < G; ++g) {
                    const float* tg = targets + ((size_t)b * G + g) * 6;
                    int labg = (int)tg[1];
                    float al = align_from(tg, base[(size_t)(64 + labg) * hw], box, ax, ay);
                    if (al > best) { best = al; gidx = g; }
                }
            } else {
                gidx = __ffs(m) - 1;
            }
            const float* t = targets + ((size_t)b * G + gidx) * 6;
            int lab = (int)t[1];
            float logit = base[(size_t)(64 + lab) * hw];
            float al = align_from(t, logit, box, ax, ay);
            float cx = t[2] * 640.f, cy = t[3] * 640.f;
            float hwd = t[4] * 320.f, hh = t[5] * 320.f;
            float tbx1 = cx - hwd, tby1 = cy - hh, tbx2 = cx + hwd, tby2 = cy + hh;
            const float eps = 1e-7f;
            float x1 = fmaxf(box.x, tbx1), y1 = fmaxf(box.y, tby1);
            float x2 = fminf(box.z, tbx2), y2 = fminf(box.w, tby2);
            float inter = fmaxf(x2 - x1, 0.f) * fmaxf(y2 - y1, 0.f);
            float w1 = fmaxf(box.z - box.x, eps), h1 = fmaxf(box.w - box.y, eps);
            float w2 = fmaxf(tbx2 - tbx1, eps), h2 = fmaxf(tby2 - tby1, eps);
            float uni = w1 * h1 + w2 * h2 - inter + eps;
            float iou = inter / uni;
            float iou_fg = fmaxf(iou, 0.f);
            float sval = (al / (amax[b * G + gidx] + 1e-9f)) * iou_fg;
            bce_s = -logit * sval;          // BCE correction for target!=0
            fg_s = 1.f;
            // CIoU
            float cw = fmaxf(box.z, tbx2) - fminf(box.x, tbx1);
            float ch = fmaxf(box.w, tby2) - fminf(box.y, tby1);
            float c2 = cw * cw + ch * ch + eps;
            float dx = box.x + box.z - tbx1 - tbx2;
            float dy = box.y + box.w - tby1 - tby2;
            float rho2 = (dx * dx + dy * dy) * 0.25f;
            float dv = atanf(w2 / h2) - atanf(w1 / h1);
            float v = 0.40528473f * dv * dv;            // 4/pi^2
            float alpha = v / (v - iou + (1.f + eps));
            float ciou = iou - (rho2 / c2 + v * alpha);
            bbox_s = 1.f - ciou;
            // DFL
            float4 lzv = ((const float4*)logZ)[idx];
            float lz[4] = {lzv.x, lzv.y, lzv.z, lzv.w};
            float lt[4] = {(ax - tbx1) / s, (ay - tby1) / s, (tbx2 - ax) / s, (tby2 - ay) / s};
            #pragma unroll
            for (int sd = 0; sd < 4; ++sd) {
                float d = fminf(fmaxf(lt[sd], 0.f), (float)RM - 1.01f);
                int tl = (int)d;
                float wl = (float)(tl + 1) - d;
                float wr = d - (float)tl;
                float xl = base[(size_t)(sd * RM + tl) * hw];
                float xr = base[(size_t)(sd * RM + tl + 1) * hw];
                dfl_s += (lz[sd] - xl) * wl + (lz[sd] - xr) * wr;
            }
        }
    }
    __shared__ float part[4][4];
    int lane = threadIdx.x & 63, wv = threadIdx.x >> 6;
    #pragma unroll
    for (int off = 32; off > 0; off >>= 1) {
        bce_s  += __shfl_down(bce_s,  off);
        bbox_s += __shfl_down(bbox_s, off);
        dfl_s  += __shfl_down(dfl_s,  off);
        fg_s   += __shfl_down(fg_s,   off);
    }
    if (lane == 0) {
        part[wv][0] = bce_s; part[wv][1] = bbox_s;
        part[wv][2] = dfl_s; part[wv][3] = fg_s;
    }
    __syncthreads();
    if (threadIdx.x == 0) {
        float s0 = 0.f, s1 = 0.f, s2 = 0.f, s3 = 0.f;
        for (int i = 0; i < 4; ++i) {
            s0 += part[i][0]; s1 += part[i][1]; s2 += part[i][2]; s3 += part[i][3];
        }
        ((float4*)partial)[blockIdx.x] = make_float4(s0, s1, s2, s3);
    }
}

// ------- Kernel 4: reduce partials, combine -------
__global__ __launch_bounds__(256) void k_final(const float* __restrict__ partial,
                                               const float* __restrict__ partial_prep,
                                               float* __restrict__ out) {
    double s0 = 0., s1 = 0., s2 = 0., s3 = 0.;
    for (int i = threadIdx.x; i < NBLK_LOSS; i += 256) {
        float4 p = ((const float4*)partial)[i];
        s0 += p.x; s1 += p.y; s2 += p.z; s3 += p.w;
    }
    for (int i = threadIdx.x; i < NBLK_PREP; i += 256)
        s0 += partial_prep[i];
    #pragma unroll
    for (int off = 32; off > 0; off >>= 1) {
        s0 += __shfl_down(s0, off);
        s1 += __shfl_down(s1, off);
        s2 += __shfl_down(s2, off);
        s3 += __shfl_down(s3, off);
    }
    __shared__ double part[4][4];
    int lane = threadIdx.x & 63, wv = threadIdx.x >> 6;
    if (lane == 0) { part[wv][0] = s0; part[wv][1] = s1; part[wv][2] = s2; part[wv][3] = s3; }
    __syncthreads();
    if (threadIdx.x == 0) {
        double bce = 0., bbox = 0., dfl = 0., fgc = 0.;
        for (int i = 0; i < 4; ++i) {
            bce += part[i][0]; bbox += part[i][1]; dfl += part[i][2]; fgc += part[i][3];
        }
        double l_cls = bce / (double)A_TOT;
        double np_ = fmax(fgc, 1.0);
        double l_bbox = 7.5 * bbox / np_;
        double l_dfl = 1.5 * dfl / np_;
        out[0] = (float)(l_cls + l_bbox + l_dfl);
        out[1] = (float)l_cls;
        out[2] = (float)l_bbox;
        out[3] = 0.f;
        out[4] = (float)l_dfl;
    }
}

extern "C" void kernel_launch(void* const* d_in, const int* in_sizes, int n_in,
                              void* d_out, int out_size, void* d_ws, size_t ws_size,
                              hipStream_t stream) {
    const float* p0 = (const float*)d_in[0];
    const float* p1 = (const float*)d_in[1];
    const float* p2 = (const float*)d_in[2];
    const float* targets = (const float*)d_in[3];
    float* out = (float*)d_out;

    char* ws = (char*)d_ws;
    size_t off = 0;
    float* pd_boxes = (float*)(ws + off); off += (size_t)NBA * 4 * sizeof(float);
    float* logZ     = (float*)(ws + off); off += (size_t)NBA * 4 * sizeof(float);
    float* amax     = (float*)(ws + off); off += (size_t)BSZ * G * sizeof(float);
    unsigned int* mask = (unsigned int*)(ws + off); off += (size_t)NBA * sizeof(unsigned int);
    float* partial  = (float*)(ws + off); off += (size_t)NBLK_LOSS * 4 * sizeof(float);
    float* partial_prep = (float*)(ws + off); off += (size_t)NBLK_PREP * sizeof(float);

    k_prep<<<NBLK_PREP, 256, 0, stream>>>(p0, p1, p2, pd_boxes, logZ, mask, partial_prep);
    k_align<<<BSZ * G, 256, 0, stream>>>(targets, pd_boxes, p0, p1, p2, amax, mask);
    k_loss<<<NBLK_LOSS, 256, 0, stream>>>(targets, pd_boxes, logZ, amax, mask,
                                          p0, p1, p2, partial);
    k_final<<<1, 256, 0, stream>>>(partial, partial_prep, out);
}